// Round 1
// baseline (62.101 us; speedup 1.0000x reference)
//
#include <hip/hip_runtime.h>
#include <math.h>

#define NPRIMES 32
#define MAXK    19
#define TAU     0.01f

// _soft_sort_asc(x, TAU) from the reference, returning out[want_idx].
// Reference math: w_i = (n-i)/tau (i=0..n-1); s = ascending sort of (-x)
// (i.e. s_i = -x_desc_i); y = w - s; sol = isotonic non-increasing fit of y
// (PAV); out = -(w - sol) = sol - w.
__device__ __forceinline__ float soft_sort_pick(float* x, int n, int want_idx) {
    // sort x descending (insertion sort; n <= 19)
    for (int i = 1; i < n; ++i) {
        float v = x[i];
        int j = i - 1;
        while (j >= 0 && x[j] < v) { x[j + 1] = x[j]; --j; }
        x[j + 1] = v;
    }
    // y_i = w_i - s_i = (n-i)/tau + x_desc_i
    float y[MAXK];
    for (int i = 0; i < n; ++i)
        y[i] = (float)(n - i) / TAU + x[i];
    // PAV: non-increasing isotonic regression of y.
    // Violation = later block mean exceeds earlier block mean -> merge.
    float bsum[MAXK];
    int   bcnt[MAXK];
    int nb = 0;
    for (int i = 0; i < n; ++i) {
        bsum[nb] = y[i];
        bcnt[nb] = 1;
        ++nb;
        while (nb >= 2 &&
               bsum[nb - 1] * (float)bcnt[nb - 2] > bsum[nb - 2] * (float)bcnt[nb - 1]) {
            bsum[nb - 2] += bsum[nb - 1];
            bcnt[nb - 2] += bcnt[nb - 1];
            --nb;
        }
    }
    // fitted value at want_idx
    float sol = 0.0f;
    int idx = 0;
    for (int b = 0; b < nb; ++b) {
        float m = bsum[b] / (float)bcnt[b];
        for (int c = 0; c < bcnt[b]; ++c) {
            if (idx == want_idx) sol = m;
            ++idx;
        }
    }
    return sol - (float)(n - want_idx) / TAU;
}

// _soft_exponents for one prime (scalar).
__device__ __forceinline__ float soft_exponent(float n, float p, float lp) {
    float ratio = n / p;
    float frac  = ratio - rintf(ratio);           // jnp.round = half-even; frac^2 used
    float t  = expf(-200.0f * frac * frac);       // ALPHA = 200
    float t2 = t * t, t4 = t2 * t2, t8 = t4 * t4; // ^MASK_POWER(8)
    float denom  = ratio + ((ratio == 0.0f) ? 1.0f : 0.0f);
    float mask_p = t8 * (ratio / denom);
    float max_k = floorf(logf(n) / lp);

    float scores[MAXK];
    float pk = 1.0f;
    for (int k = 1; k <= MAXK; ++k) {
        pk = pk * p;                               // p^k (inf for huge -> gated anyway)
        float r  = n / pk;
        float fr = r - rintf(r);
        float mk = expf(-2560.0f * fr * fr);       // BETA = 2560
        float sc = mk * (float)k;
        scores[k - 1] = ((float)k <= max_k) ? sc : 0.0f;
    }
    // sorted_scores[:, -1]
    float k_hat = soft_sort_pick(scores, MAXK, MAXK - 1);
    return ((mask_p >= 0.99f) && (max_k >= 1.0f)) ? k_hat : 0.0f;
}

__global__ void softgcd_kernel(const float* __restrict__ n1p,
                               const float* __restrict__ n2p,
                               const float* __restrict__ primes,
                               const float* __restrict__ logp,
                               float* __restrict__ out) {
    const int lane = threadIdx.x;  // one wave64; lanes 0..31 own one prime each
    float contrib = 0.0f;
    if (lane < NPRIMES) {
        const float p  = primes[lane];
        const float lp = logp[lane];
        const float n1 = n1p[0];
        const float n2 = n2p[0];
        const float e1 = soft_exponent(n1, p, lp);
        const float e2 = soft_exponent(n2, p, lp);
        float pair[MAXK];   // only first 2 entries used
        pair[0] = e1;
        pair[1] = e2;
        const float min_exp = soft_sort_pick(pair, 2, 0);  // sorted_pair[:, 0]
        contrib = min_exp * lp;
    }
    // wave64 shuffle reduction (lanes >= 32 carry 0)
    for (int off = 32; off > 0; off >>= 1)
        contrib += __shfl_down(contrib, off, 64);
    if (lane == 0)
        out[0] = expf(contrib);
}

extern "C" void kernel_launch(void* const* d_in, const int* in_sizes, int n_in,
                              void* d_out, int out_size, void* d_ws, size_t ws_size,
                              hipStream_t stream) {
    const float* n1     = (const float*)d_in[0];
    const float* n2     = (const float*)d_in[1];
    const float* primes = (const float*)d_in[2];
    const float* logp   = (const float*)d_in[3];
    float* out = (float*)d_out;
    softgcd_kernel<<<dim3(1), dim3(64), 0, stream>>>(n1, n2, primes, logp, out);
}

// Round 2
// 12.595 us; speedup vs baseline: 4.9306x; 4.9306x over previous
//
#include <hip/hip_runtime.h>
#include <math.h>

#define NPRIMES 32
#define MAXK    19
#define TAU     0.01f
#define FLT_BIG 3.402823466e+38f

// Soft exponent v_p(n) for one prime, scalar per lane, fully register-resident.
// Faithful to the reference:
//   scores[k-1] = exp(-BETA*fr^2)*k gated by k <= max_k
//   soft_sort_asc(scores, tau)[-1]  ==  sol_{n-1} - w_{n-1}
// where sol is the non-increasing isotonic fit of y = w - s (min-max formula).
__device__ __forceinline__ float soft_exponent(float n, float p, float lp) {
    // mask_p
    float ratio = n / p;
    float frac  = ratio - rintf(ratio);              // jnp.round = half-even
    float t  = expf(-200.0f * frac * frac);          // ALPHA
    float t2 = t * t, t4 = t2 * t2, t8 = t4 * t4;    // ^MASK_POWER(8)
    float denom  = ratio + ((ratio == 0.0f) ? 1.0f : 0.0f);
    float mask_p = t8 * (ratio / denom);
    float max_k  = floorf(logf(n) / lp);

    // scores (registers; unrolled)
    float s[MAXK];
    float pk = 1.0f;
#pragma unroll
    for (int k = 1; k <= MAXK; ++k) {
        pk *= p;
        float r  = n / pk;
        float fr = r - rintf(r);
        float mk = expf(-2560.0f * fr * fr);         // BETA
        float sc = mk * (float)k;
        s[k - 1] = ((float)k <= max_k) ? sc : 0.0f;
    }

    // sort descending: odd-even transposition network, 19 rounds, all
    // compile-time indices -> stays in VGPRs.
#pragma unroll
    for (int r = 0; r < MAXK; ++r) {
#pragma unroll
        for (int i = (r & 1); i + 1 < MAXK; i += 2) {
            float a = s[i], b = s[i + 1];
            s[i]     = fmaxf(a, b);
            s[i + 1] = fminf(a, b);
        }
    }

    // z_i = -(w_i + s_desc_i), w_i = (MAXK-i)/tau ; cs = [0, cumsum(z)]
    float cs[MAXK + 1];
    cs[0] = 0.0f;
#pragma unroll
    for (int i = 0; i < MAXK; ++i) {
        float y = (float)(MAXK - i) / TAU + s[i];
        cs[i + 1] = cs[i] - y;
    }

    // min-max isotonic formula, evaluated only at index n-1:
    //   v = max_j min_{k>=j} (cs[k+1]-cs[j])/(k-j+1)
    // (all 361 divides independent -> pipelined, no scratch)
    float v = -FLT_BIG;
#pragma unroll
    for (int j = 0; j < MAXK; ++j) {
        float m = FLT_BIG;
#pragma unroll
        for (int k = j; k < MAXK; ++k) {
            float mean = (cs[k + 1] - cs[j]) / (float)(k - j + 1);
            m = fminf(m, mean);
        }
        v = fmaxf(v, m);
    }
    // out[-1] = sol_{n-1} - w_{n-1} = -v - 1/tau
    float k_hat = -v - (1.0f / TAU);

    return ((mask_p >= 0.99f) && (max_k >= 1.0f)) ? k_hat : 0.0f;
}

__global__ void softgcd_kernel(const float* __restrict__ n1p,
                               const float* __restrict__ n2p,
                               const float* __restrict__ primes,
                               const float* __restrict__ logp,
                               float* __restrict__ out) {
    const int lane  = threadIdx.x;        // one wave64
    const int pidx  = lane >> 1;          // prime index 0..31
    const int which = lane & 1;           // 0 -> n1, 1 -> n2

    const float p  = primes[pidx];
    const float lp = logp[pidx];
    const float n  = which ? n2p[0] : n1p[0];

    const float e  = soft_exponent(n, p, lp);
    const float ep = __shfl_xor(e, 1, 64);   // partner's exponent

    // pair soft-sort (n=2), element [0]:
    //   w=[200,100]; y=[200+hi, 100+lo]; z=-y
    //   v0 = min(z0, (z0+z1)/2); out0 = -v0 - 200
    const float hi = fmaxf(e, ep);
    const float lo = fminf(e, ep);
    const float z0 = -(200.0f + hi);
    const float z1 = -(100.0f + lo);
    const float v0 = fminf(z0, (z0 + z1) * 0.5f);   // /2 exact
    const float out0 = -v0 - 200.0f;

    float contrib = which ? 0.0f : out0 * lp;   // count each prime once

    // wave64 shuffle reduction
    for (int off = 32; off > 0; off >>= 1)
        contrib += __shfl_down(contrib, off, 64);
    if (lane == 0)
        out[0] = expf(contrib);
}

extern "C" void kernel_launch(void* const* d_in, const int* in_sizes, int n_in,
                              void* d_out, int out_size, void* d_ws, size_t ws_size,
                              hipStream_t stream) {
    const float* n1     = (const float*)d_in[0];
    const float* n2     = (const float*)d_in[1];
    const float* primes = (const float*)d_in[2];
    const float* logp   = (const float*)d_in[3];
    float* out = (float*)d_out;
    softgcd_kernel<<<dim3(1), dim3(64), 0, stream>>>(n1, n2, primes, logp, out);
}

// Round 3
// 9.665 us; speedup vs baseline: 6.4253x; 1.3031x over previous
//
#include <hip/hip_runtime.h>
#include <math.h>

#define NPRIMES 32
#define MAXK    19
#define TAU     0.01f

// exp(x) = exp2(x * log2(e)); fold the scale into the Gaussian constants.
// -200*8*log2e  (mask: expf(-200 f^2)^8)
#define MASK_C  (-2308.3120655f)
// -2560*log2e   (score gaussians)
#define BETA_C  (-3693.2993047f)

// Soft exponent v_p(n) for one prime, scalar per lane, register-resident.
// soft_sort_asc(scores, tau)[-1] collapses exactly (see theory): with
// z strictly increasing (steps >= 81), the reference's min-max isotonic
// formula selects the j=k=n-1 candidate, whose value is the f32 expression
// (cs[19]-cs[18])/1.0 on the rounded cumsum. We reproduce that bit-for-bit.
__device__ __forceinline__ float soft_exponent(float n, float p, float lp) {
    // mask_p
    float ratio  = n / p;
    float frac   = ratio - rintf(ratio);            // jnp.round = half-even
    float mask_p = exp2f(MASK_C * frac * frac);     // == expf(-200 f^2)^8
    float denom  = ratio + ((ratio == 0.0f) ? 1.0f : 0.0f);
    mask_p      *= ratio / denom;
    float max_k  = floorf(logf(n) / lp);

    // scores (registers; unrolled)
    float s[MAXK];
    float pk = 1.0f;
#pragma unroll
    for (int k = 1; k <= MAXK; ++k) {
        pk *= p;                                    // p^k (inf for huge -> underflow path)
        float r  = n / pk;                          // IEEE divide: exact for true divisors
        float fr = r - rintf(r);
        float mk = exp2f(BETA_C * fr * fr);         // == expf(-2560 fr^2)
        s[k - 1] = ((float)k <= max_k) ? mk * (float)k : 0.0f;
    }

    // sort descending: odd-even transposition network, compile-time indices.
#pragma unroll
    for (int r = 0; r < MAXK; ++r) {
#pragma unroll
        for (int i = (r & 1); i + 1 < MAXK; i += 2) {
            float a = s[i], b = s[i + 1];
            s[i]     = fmaxf(a, b);
            s[i + 1] = fminf(a, b);
        }
    }

    // Sequential cumsum of z_i = -(w_i + s_desc_i), w_i = (MAXK-i)/tau
    // (w constants fold exactly to 100*(MAXK-i) at compile time).
    // Keep cs[18] and cs[19]; k_hat = -(cs19 - cs18) - w[18].
    float cs = 0.0f, cs18 = 0.0f;
#pragma unroll
    for (int i = 0; i < MAXK; ++i) {
        if (i == MAXK - 1) cs18 = cs;
        float y = (float)(MAXK - i) / TAU + s[i];
        cs = cs - y;
    }
    float v     = cs - cs18;                        // selected isotonic candidate
    float k_hat = -v - (1.0f / TAU);

    return ((mask_p >= 0.99f) && (max_k >= 1.0f)) ? k_hat : 0.0f;
}

__global__ void softgcd_kernel(const float* __restrict__ n1p,
                               const float* __restrict__ n2p,
                               const float* __restrict__ primes,
                               const float* __restrict__ logp,
                               float* __restrict__ out) {
    const int lane  = threadIdx.x;        // one wave64
    const int pidx  = lane >> 1;          // prime index 0..31
    const int which = lane & 1;           // 0 -> n1, 1 -> n2

    const float p  = primes[pidx];
    const float lp = logp[pidx];
    const float n  = which ? n2p[0] : n1p[0];

    const float e  = soft_exponent(n, p, lp);
    const float ep = __shfl_xor(e, 1, 64);   // partner's exponent

    // pair soft-sort (n=2), element [0]: collapses to max (same no-pooling
    // argument; verified absmax 0 in rounds 1-2).
    const float hi = fmaxf(e, ep);
    const float lo = fminf(e, ep);
    const float z0 = -(200.0f + hi);
    const float z1 = -(100.0f + lo);
    const float v0 = fminf(z0, (z0 + z1) * 0.5f);
    const float out0 = -v0 - 200.0f;

    float contrib = which ? 0.0f : out0 * lp;   // count each prime once

    // wave64 shuffle reduction
    for (int off = 32; off > 0; off >>= 1)
        contrib += __shfl_down(contrib, off, 64);
    if (lane == 0)
        out[0] = expf(contrib);
}

extern "C" void kernel_launch(void* const* d_in, const int* in_sizes, int n_in,
                              void* d_out, int out_size, void* d_ws, size_t ws_size,
                              hipStream_t stream) {
    const float* n1     = (const float*)d_in[0];
    const float* n2     = (const float*)d_in[1];
    const float* primes = (const float*)d_in[2];
    const float* logp   = (const float*)d_in[3];
    float* out = (float*)d_out;
    softgcd_kernel<<<dim3(1), dim3(64), 0, stream>>>(n1, n2, primes, logp, out);
}